// Round 3
// baseline (322.171 us; speedup 1.0000x reference)
//
#include <hip/hip_runtime.h>

#define T_SEQ 2048
#define DM 1024
#define NH 16
#define HD 64
// SCALE * log2(e) : softmax computed in exp2 domain
#define SC2 0.1803368801111731f
#define LS 80   // LDS row stride (u16), conflict-free for 16-row b128 reads

typedef unsigned short u16;
typedef unsigned int u32;
typedef __attribute__((ext_vector_type(8))) short bf16x8;
typedef __attribute__((ext_vector_type(4))) float f32x4;

static __device__ __forceinline__ f32x4 mfma16(bf16x8 a, bf16x8 b, f32x4 c) {
    return __builtin_amdgcn_mfma_f32_16x16x32_bf16(a, b, c, 0, 0, 0);
}
static __device__ __forceinline__ float bf2f(u16 u) {
    union { u32 i; float f; } v; v.i = ((u32)u) << 16; return v.f;
}
static __device__ __forceinline__ u16 f2bf(float f) {
    union { float f; u32 i; } v; v.f = f;
    u32 x = v.i;
    x += 0x7FFFu + ((x >> 16) & 1u);   // RNE
    return (u16)(x >> 16);
}
static __device__ __forceinline__ u32 pk2(float lo, float hi) {
    return (u32)f2bf(lo) | ((u32)f2bf(hi) << 16);
}
// load 8 contiguous elements as packed bf16, converting from f32 if f==0
static __device__ __forceinline__ uint4 ld8(const void* src, size_t idx, int f) {
    if (f) return *(const uint4*)((const u16*)src + idx);
    const float* s = (const float*)src + idx;
    uint4 a = *(const uint4*)s;
    uint4 b = *(const uint4*)(s + 4);
    const float* af = (const float*)&a;
    const float* bf = (const float*)&b;
    uint4 r;
    r.x = pk2(af[0], af[1]); r.y = pk2(af[2], af[3]);
    r.z = pk2(bf[0], bf[1]); r.w = pk2(bf[2], bf[3]);
    return r;
}
static __device__ __forceinline__ float qsum16(float v) {
#pragma unroll
    for (int o = 1; o < 16; o <<= 1) v += __shfl_xor(v, o, 64);
    return v;
}
static __device__ __forceinline__ float ex2(float x) {
    return __builtin_amdgcn_exp2f(x);
}

// ---------------------------------------------------------------------------
// dtype detection + lambda. bf16 N(0,1) samples at even u16s have exponent
// field in [110,140] ~always; f32 mantissa halves hit ~12%.
// ---------------------------------------------------------------------------
__global__ void detect_lam(const u16* __restrict__ x, const void* __restrict__ lamsrc,
                           int* __restrict__ flag, float* __restrict__ lamf) {
    __shared__ int tot;
    if (threadIdx.x == 0) tot = 0;
    __syncthreads();
    int c = 0;
    for (int i = threadIdx.x; i < 1024; i += 256) {
        u16 v = x[2 * i];
        int e = (v >> 7) & 0xFF;
        c += (e >= 110 && e <= 140) ? 1 : 0;
    }
    atomicAdd(&tot, c);
    __syncthreads();
    const int f = (tot >= 512) ? 1 : 0;
    if (threadIdx.x == 0) *flag = f;
    if (threadIdx.x < NH) {
        float v = f ? bf2f(((const u16*)lamsrc)[threadIdx.x])
                    : ((const float*)lamsrc)[threadIdx.x];
        lamf[threadIdx.x] = 1.0f / (1.0f + __expf(-v));
    }
}

// ---------------------------------------------------------------------------
// Fused QKV(+V-transpose) projection GEMM, inline dtype convert, register-
// prefetch pipeline. Tile 128x128xK64, 4 waves 2x2, wave 64x64 (4x4 subtiles).
// grid.x = 32 (4 weights x 8 n-tiles), grid.y = 16 (m-tiles).
// ---------------------------------------------------------------------------
__global__ __launch_bounds__(256) void qkv_gemm(
    const void* __restrict__ xs, const void* __restrict__ wq,
    const void* __restrict__ wk1, const void* __restrict__ wk2,
    const void* __restrict__ wv, const int* __restrict__ flag,
    u16* __restrict__ qd, u16* __restrict__ k1d, u16* __restrict__ k2d,
    u16* __restrict__ vtd) {
    __shared__ __align__(16) u16 As[128 * 72];
    __shared__ __align__(16) u16 Bs[128 * 72];

    const int f = *flag;
    const int nt = blockIdx.x;
    const int mt = blockIdx.y;
    const int w = nt >> 3;
    const int n0 = (nt & 7) * 128;
    const int m0 = mt * 128;
    const void* Bp = (w == 0) ? wq : (w == 1) ? wk1 : (w == 2) ? wk2 : wv;

    const int tid = threadIdx.x;
    const int lane = tid & 63, wave = tid >> 6;
    const int lr = lane & 15, quad = lane >> 4;
    const int wm = (wave >> 1) * 64, wn = (wave & 1) * 64;
    const int srow = tid >> 3, scol = (tid & 7) * 8;   // staging coords (per it: +32 rows)

    f32x4 acc[4][4];
#pragma unroll
    for (int i = 0; i < 4; i++)
#pragma unroll
        for (int j = 0; j < 4; j++) acc[i][j] = (f32x4){0.f, 0.f, 0.f, 0.f};

    uint4 ar[4], br[4];
#pragma unroll
    for (int it = 0; it < 4; it++) {
        ar[it] = ld8(xs, (size_t)(m0 + it * 32 + srow) * DM + scol, f);
        br[it] = ld8(Bp, (size_t)(n0 + it * 32 + srow) * DM + scol, f);
    }

    for (int k0 = 0; k0 < DM; k0 += 64) {
        __syncthreads();
#pragma unroll
        for (int it = 0; it < 4; it++) {
            *(uint4*)(&As[(it * 32 + srow) * 72 + scol]) = ar[it];
            *(uint4*)(&Bs[(it * 32 + srow) * 72 + scol]) = br[it];
        }
        __syncthreads();
        if (k0 + 64 < DM) {
#pragma unroll
            for (int it = 0; it < 4; it++) {
                ar[it] = ld8(xs, (size_t)(m0 + it * 32 + srow) * DM + k0 + 64 + scol, f);
                br[it] = ld8(Bp, (size_t)(n0 + it * 32 + srow) * DM + k0 + 64 + scol, f);
            }
        }
#pragma unroll
        for (int kk = 0; kk < 64; kk += 32) {
            bf16x8 af[4], bfr[4];
#pragma unroll
            for (int i = 0; i < 4; i++)
                af[i] = *(const bf16x8*)(&As[(wm + i * 16 + lr) * 72 + kk + quad * 8]);
#pragma unroll
            for (int j = 0; j < 4; j++)
                bfr[j] = *(const bf16x8*)(&Bs[(wn + j * 16 + lr) * 72 + kk + quad * 8]);
#pragma unroll
            for (int i = 0; i < 4; i++)
#pragma unroll
                for (int j = 0; j < 4; j++) acc[i][j] = mfma16(af[i], bfr[j], acc[i][j]);
        }
    }

#pragma unroll
    for (int i = 0; i < 4; i++)
#pragma unroll
        for (int j = 0; j < 4; j++)
#pragma unroll
            for (int r = 0; r < 4; r++) {
                int t = m0 + wm + i * 16 + quad * 4 + r;
                int o = n0 + wn + j * 16 + lr;
                u16 vbits = f2bf(acc[i][j][r]);
                int hh = o >> 6, d0 = o & 63;
                if (w == 3)
                    vtd[((size_t)hh * HD + d0) * T_SEQ + t] = vbits;   // v transposed
                else
                    ((w == 0) ? qd : (w == 1) ? k1d : k2d)[((size_t)hh * T_SEQ + t) * HD + d0] = vbits;
            }
}

// ---------------------------------------------------------------------------
// Two-pass max-free differential flash attention, register-prefetch pipeline.
// Q fragments in regs (direct global), V direct global->B-fragment regs,
// K1/K2 double-staged via regs->LDS. Only the diagonal tile is masked.
// Grid 512: h = b&15, i = b>>4, qt = i<16 ? i : 47-i (CU-pair balance).
// ---------------------------------------------------------------------------
__global__ __launch_bounds__(256) void attn_kernel(
    const u16* __restrict__ qg, const u16* __restrict__ k1g,
    const u16* __restrict__ k2g, const u16* __restrict__ vtg,
    const float* __restrict__ lamf, u16* __restrict__ ao) {
    __shared__ __align__(16) u16 k1s[64 * LS];
    __shared__ __align__(16) u16 k2s[64 * LS];
    __shared__ __align__(16) u16 ps[4][16 * LS];

    const int b = blockIdx.x;
    const int h = b & 15;
    const int bi = b >> 4;
    const int qt = (bi < 16) ? bi : 47 - bi;
    const int t0 = qt * 64;
    const int tid = threadIdx.x;
    const int lane = tid & 63, wave = tid >> 6;
    const int lr = lane & 15, quad = lane >> 4;
    const int wm = wave * 16;
    const float lam = lamf[h];
    const int srow = tid >> 3, scol = (tid & 7) * 8;

    const u16* qh = qg + (size_t)h * T_SEQ * HD;
    const u16* k1h = k1g + (size_t)h * T_SEQ * HD;
    const u16* k2h = k2g + (size_t)h * T_SEQ * HD;
    const u16* vh = vtg + (size_t)h * HD * T_SEQ;

    // Q A-fragments straight from global: row t0+wm+lr, cols kk+quad*8
    bf16x8 aq[2];
#pragma unroll
    for (int kk = 0; kk < 2; kk++)
        aq[kk] = *(const bf16x8*)(&qh[(size_t)(t0 + wm + lr) * HD + kk * 32 + quad * 8]);

    const int nkt = qt + 1;
    uint4 k1r[2], k2r[2];
#pragma unroll
    for (int it = 0; it < 2; it++) {
        k1r[it] = *(const uint4*)(&k1h[(size_t)(it * 32 + srow) * HD + scol]);
        k2r[it] = *(const uint4*)(&k2h[(size_t)(it * 32 + srow) * HD + scol]);
    }

    // ---------------- pass A: per-lane Z accumulation ----------------
    float z1a[4] = {0.f, 0.f, 0.f, 0.f}, z2a[4] = {0.f, 0.f, 0.f, 0.f};

    for (int kt = 0; kt < nkt; kt++) {
        __syncthreads();
#pragma unroll
        for (int it = 0; it < 2; it++) {
            *(uint4*)(&k1s[(it * 32 + srow) * LS + scol]) = k1r[it];
            *(uint4*)(&k2s[(it * 32 + srow) * LS + scol]) = k2r[it];
        }
        __syncthreads();
        if (kt + 1 < nkt) {
#pragma unroll
            for (int it = 0; it < 2; it++) {
                k1r[it] = *(const uint4*)(&k1h[(size_t)((kt + 1) * 64 + it * 32 + srow) * HD + scol]);
                k2r[it] = *(const uint4*)(&k2h[(size_t)((kt + 1) * 64 + it * 32 + srow) * HD + scol]);
            }
        }

        f32x4 sa[4], sb[4];
#pragma unroll
        for (int j = 0; j < 4; j++) { sa[j] = (f32x4){0.f,0.f,0.f,0.f}; sb[j] = (f32x4){0.f,0.f,0.f,0.f}; }
#pragma unroll
        for (int kk = 0; kk < 2; kk++) {
            bf16x8 b1[4], b2[4];
#pragma unroll
            for (int j = 0; j < 4; j++) {
                b1[j] = *(const bf16x8*)(&k1s[(j * 16 + lr) * LS + kk * 32 + quad * 8]);
                b2[j] = *(const bf16x8*)(&k2s[(j * 16 + lr) * LS + kk * 32 + quad * 8]);
            }
#pragma unroll
            for (int j = 0; j < 4; j++) { sa[j] = mfma16(aq[kk], b1[j], sa[j]); sb[j] = mfma16(aq[kk], b2[j], sb[j]); }
        }

        if (kt < qt) {  // fully unmasked tile
#pragma unroll
            for (int r = 0; r < 4; r++)
#pragma unroll
                for (int j = 0; j < 4; j++) {
                    z1a[r] += ex2(sa[j][r] * SC2);
                    z2a[r] += ex2(sb[j][r] * SC2);
                }
        } else {        // diagonal tile
#pragma unroll
            for (int r = 0; r < 4; r++) {
                const int grow = t0 + wm + quad * 4 + r;
#pragma unroll
                for (int j = 0; j < 4; j++) {
                    int gcol = kt * 64 + j * 16 + lr;
                    if (gcol <= grow) {
                        z1a[r] += ex2(sa[j][r] * SC2);
                        z2a[r] += ex2(sb[j][r] * SC2);
                    }
                }
            }
        }
    }

    float z1i[4], z2i[4];
#pragma unroll
    for (int r = 0; r < 4; r++) {
        z1i[r] = 1.f / qsum16(z1a[r]);
        z2i[r] = lam / qsum16(z2a[r]);
    }

    f32x4 oac[4];
#pragma unroll
    for (int j = 0; j < 4; j++) oac[j] = (f32x4){0.f, 0.f, 0.f, 0.f};
    float dacc[4] = {0.f, 0.f, 0.f, 0.f};

    // reload tile 0 for pass B
#pragma unroll
    for (int it = 0; it < 2; it++) {
        k1r[it] = *(const uint4*)(&k1h[(size_t)(it * 32 + srow) * HD + scol]);
        k2r[it] = *(const uint4*)(&k2h[(size_t)(it * 32 + srow) * HD + scol]);
    }

    // ---------------- pass B: P, per-lane denom, PV ----------------
    for (int kt = 0; kt < nkt; kt++) {
        __syncthreads();
#pragma unroll
        for (int it = 0; it < 2; it++) {
            *(uint4*)(&k1s[(it * 32 + srow) * LS + scol]) = k1r[it];
            *(uint4*)(&k2s[(it * 32 + srow) * LS + scol]) = k2r[it];
        }
        __syncthreads();
        if (kt + 1 < nkt) {
#pragma unroll
            for (int it = 0; it < 2; it++) {
                k1r[it] = *(const uint4*)(&k1h[(size_t)((kt + 1) * 64 + it * 32 + srow) * HD + scol]);
                k2r[it] = *(const uint4*)(&k2h[(size_t)((kt + 1) * 64 + it * 32 + srow) * HD + scol]);
            }
        }
        // V tile direct to B-fragment regs: B[n=j*16+lr][k=kk*32+quad*8..]
        bf16x8 vb[2][4];
#pragma unroll
        for (int kk = 0; kk < 2; kk++)
#pragma unroll
            for (int j = 0; j < 4; j++)
                vb[kk][j] = *(const bf16x8*)(&vh[(size_t)(j * 16 + lr) * T_SEQ + kt * 64 + kk * 32 + quad * 8]);

        f32x4 sa[4], sb[4];
#pragma unroll
        for (int j = 0; j < 4; j++) { sa[j] = (f32x4){0.f,0.f,0.f,0.f}; sb[j] = (f32x4){0.f,0.f,0.f,0.f}; }
#pragma unroll
        for (int kk = 0; kk < 2; kk++) {
            bf16x8 b1[4], b2[4];
#pragma unroll
            for (int j = 0; j < 4; j++) {
                b1[j] = *(const bf16x8*)(&k1s[(j * 16 + lr) * LS + kk * 32 + quad * 8]);
                b2[j] = *(const bf16x8*)(&k2s[(j * 16 + lr) * LS + kk * 32 + quad * 8]);
            }
#pragma unroll
            for (int j = 0; j < 4; j++) { sa[j] = mfma16(aq[kk], b1[j], sa[j]); sb[j] = mfma16(aq[kk], b2[j], sb[j]); }
        }

        if (kt < qt) {
#pragma unroll
            for (int r = 0; r < 4; r++)
#pragma unroll
                for (int j = 0; j < 4; j++) {
                    float p = ex2(sa[j][r] * SC2) * z1i[r] - ex2(sb[j][r] * SC2) * z2i[r];
                    dacc[r] += fabsf(p);
                    ps[wave][(quad * 4 + r) * LS + j * 16 + lr] = f2bf(p);
                }
        } else {
#pragma unroll
            for (int r = 0; r < 4; r++) {
                const int grow = t0 + wm + quad * 4 + r;
#pragma unroll
                for (int j = 0; j < 4; j++) {
                    int gcol = kt * 64 + j * 16 + lr;
                    float p = 0.f;
                    if (gcol <= grow)
                        p = ex2(sa[j][r] * SC2) * z1i[r] - ex2(sb[j][r] * SC2) * z2i[r];
                    dacc[r] += fabsf(p);
                    ps[wave][(quad * 4 + r) * LS + j * 16 + lr] = f2bf(p);
                }
            }
        }

        // PV: wave-local LDS round trip (DS pipe in-order per wave)
#pragma unroll
        for (int kk = 0; kk < 2; kk++) {
            bf16x8 pa = *(const bf16x8*)(&ps[wave][lr * LS + kk * 32 + quad * 8]);
#pragma unroll
            for (int j = 0; j < 4; j++) oac[j] = mfma16(pa, vb[kk][j], oac[j]);
        }
    }

    float dnm[4];
#pragma unroll
    for (int r = 0; r < 4; r++) dnm[r] = 1.f / fmaxf(qsum16(dacc[r]), 1e-6f);
#pragma unroll
    for (int j = 0; j < 4; j++)
#pragma unroll
        for (int r = 0; r < 4; r++) {
            int rowl = wm + quad * 4 + r;
            float val = oac[j][r] * dnm[r];
            ao[(size_t)(t0 + rowl) * DM + h * HD + j * 16 + lr] = f2bf(val);
        }
}

// ---------------------------------------------------------------------------
// Output GEMM: out = ao @ Wo^T. 128x64 tiles -> 256 blocks (all CUs busy),
// inline Wo convert, register prefetch. Wave: 64x32 (4x2 subtiles).
// ---------------------------------------------------------------------------
__global__ __launch_bounds__(256) void out_gemm(
    const u16* __restrict__ ab, const void* __restrict__ wo,
    const int* __restrict__ flag, void* __restrict__ outp) {
    __shared__ __align__(16) u16 As[128 * 72];
    __shared__ __align__(16) u16 Bs[64 * 72];

    const int f = *flag;
    const int n0 = blockIdx.x * 64;    // 0..15
    const int m0 = blockIdx.y * 128;   // 0..15
    const int tid = threadIdx.x;
    const int lane = tid & 63, wave = tid >> 6;
    const int lr = lane & 15, quad = lane >> 4;
    const int wm = (wave >> 1) * 64, wn = (wave & 1) * 32;
    const int srow = tid >> 3, scol = (tid & 7) * 8;

    f32x4 acc[4][2];
#pragma unroll
    for (int i = 0; i < 4; i++)
#pragma unroll
        for (int j = 0; j < 2; j++) acc[i][j] = (f32x4){0.f, 0.f, 0.f, 0.f};

    uint4 ar[4], br[2];
#pragma unroll
    for (int it = 0; it < 4; it++)
        ar[it] = *(const uint4*)(&ab[(size_t)(m0 + it * 32 + srow) * DM + scol]);
#pragma unroll
    for (int it = 0; it < 2; it++)
        br[it] = ld8(wo, (size_t)(n0 + it * 32 + srow) * DM + scol, f);

    for (int k0 = 0; k0 < DM; k0 += 64) {
        __syncthreads();
#pragma unroll
        for (int it = 0; it < 4; it++)
            *(uint4*)(&As[(it * 32 + srow) * 72 + scol]) = ar[it];
#pragma unroll
        for (int it = 0; it < 2; it++)
            *(uint4*)(&Bs[(it * 32 + srow) * 72 + scol]) = br[it];
        __syncthreads();
        if (k0 + 64 < DM) {
#pragma unroll
            for (int it = 0; it < 4; it++)
                ar[it] = *(const uint4*)(&ab[(size_t)(m0 + it * 32 + srow) * DM + k0 + 64 + scol]);
#pragma unroll
            for (int it = 0; it < 2; it++)
                br[it] = ld8(wo, (size_t)(n0 + it * 32 + srow) * DM + k0 + 64 + scol, f);
        }
#pragma unroll
        for (int kk = 0; kk < 64; kk += 32) {
            bf16x8 af[4], bfr[2];
#pragma unroll
            for (int i = 0; i < 4; i++)
                af[i] = *(const bf16x8*)(&As[(wm + i * 16 + lr) * 72 + kk + quad * 8]);
#pragma unroll
            for (int j = 0; j < 2; j++)
                bfr[j] = *(const bf16x8*)(&Bs[(wn + j * 16 + lr) * 72 + kk + quad * 8]);
#pragma unroll
            for (int i = 0; i < 4; i++)
#pragma unroll
                for (int j = 0; j < 2; j++) acc[i][j] = mfma16(af[i], bfr[j], acc[i][j]);
        }
    }

#pragma unroll
    for (int i = 0; i < 4; i++)
#pragma unroll
        for (int j = 0; j < 2; j++)
#pragma unroll
            for (int r = 0; r < 4; r++) {
                int t = m0 + wm + i * 16 + quad * 4 + r;
                int o = n0 + wn + j * 16 + lr;
                float val = acc[i][j][r];
                if (f)
                    ((u16*)outp)[(size_t)t * DM + o] = f2bf(val);
                else
                    ((float*)outp)[(size_t)t * DM + o] = val;
            }
}

extern "C" void kernel_launch(void* const* d_in, const int* in_sizes, int n_in,
                              void* d_out, int out_size, void* d_ws, size_t ws_size,
                              hipStream_t stream) {
    char* ws = (char*)d_ws;
    int* flag = (int*)(ws + 0);
    float* lamf = (float*)(ws + 256);
    u16* qd  = (u16*)(ws + ((size_t)16 << 20));  // [H][T][64]
    u16* k1d = (u16*)(ws + ((size_t)20 << 20));
    u16* k2d = (u16*)(ws + ((size_t)24 << 20));
    u16* vtd = (u16*)(ws + ((size_t)28 << 20));  // [H][64][T]
    u16* ao  = (u16*)(ws + ((size_t)32 << 20));  // [T][DM]

    detect_lam<<<1, 256, 0, stream>>>((const u16*)d_in[0], d_in[6], flag, lamf);
    qkv_gemm<<<dim3(32, 16), 256, 0, stream>>>(d_in[0], d_in[1], d_in[2], d_in[3],
                                               d_in[4], flag, qd, k1d, k2d, vtd);
    attn_kernel<<<dim3(512), 256, 0, stream>>>(qd, k1d, k2d, vtd, lamf, ao);
    out_gemm<<<dim3(16, 16), 256, 0, stream>>>(ao, d_in[5], flag, d_out);
}

// Round 4
// 260.716 us; speedup vs baseline: 1.2357x; 1.2357x over previous
//
#include <hip/hip_runtime.h>

#define T_SEQ 2048
#define DM 1024
#define NH 16
#define HD 64
// SCALE * log2(e) : softmax computed in exp2 domain
#define SC2 0.1803368801111731f
#define LS 80   // LDS row stride (u16), conflict-free for 16-row b128 reads

typedef unsigned short u16;
typedef unsigned int u32;
typedef __attribute__((ext_vector_type(8))) short bf16x8;
typedef __attribute__((ext_vector_type(4))) float f32x4;

static __device__ __forceinline__ f32x4 mfma16(bf16x8 a, bf16x8 b, f32x4 c) {
    return __builtin_amdgcn_mfma_f32_16x16x32_bf16(a, b, c, 0, 0, 0);
}
static __device__ __forceinline__ float bf2f(u16 u) {
    union { u32 i; float f; } v; v.i = ((u32)u) << 16; return v.f;
}
static __device__ __forceinline__ u16 f2bf(float f) {
    union { float f; u32 i; } v; v.f = f;
    u32 x = v.i;
    x += 0x7FFFu + ((x >> 16) & 1u);   // RNE
    return (u16)(x >> 16);
}
static __device__ __forceinline__ u32 pk2(float lo, float hi) {
    return (u32)f2bf(lo) | ((u32)f2bf(hi) << 16);
}
// load 8 contiguous elements as packed bf16; converts from f32 if f==0.
// When f==1 this is a single uint4 load (uniform branch), no extra pressure.
static __device__ __forceinline__ uint4 ld8(const void* src, size_t idx, int f) {
    if (f) return *(const uint4*)((const u16*)src + idx);
    const float* s = (const float*)src + idx;
    uint4 a = *(const uint4*)s;
    uint4 b = *(const uint4*)(s + 4);
    const float* af = (const float*)&a;
    const float* bf = (const float*)&b;
    uint4 r;
    r.x = pk2(af[0], af[1]); r.y = pk2(af[2], af[3]);
    r.z = pk2(bf[0], bf[1]); r.w = pk2(bf[2], bf[3]);
    return r;
}
static __device__ __forceinline__ float qsum16(float v) {
#pragma unroll
    for (int o = 1; o < 16; o <<= 1) v += __shfl_xor(v, o, 64);
    return v;
}
static __device__ __forceinline__ float ex2(float x) {
    return __builtin_amdgcn_exp2f(x);
}

// ---------------------------------------------------------------------------
// dtype detection + lambda. bf16 N(0,1) samples at even u16s have exponent
// field in [110,140] ~always; f32 mantissa halves hit ~12%.
// ---------------------------------------------------------------------------
__global__ void detect_lam(const u16* __restrict__ x, const void* __restrict__ lamsrc,
                           int* __restrict__ flag, float* __restrict__ lamf) {
    __shared__ int tot;
    if (threadIdx.x == 0) tot = 0;
    __syncthreads();
    int c = 0;
    for (int i = threadIdx.x; i < 1024; i += 256) {
        u16 v = x[2 * i];
        int e = (v >> 7) & 0xFF;
        c += (e >= 110 && e <= 140) ? 1 : 0;
    }
    atomicAdd(&tot, c);
    __syncthreads();
    const int f = (tot >= 512) ? 1 : 0;
    if (threadIdx.x == 0) *flag = f;
    if (threadIdx.x < NH) {
        float v = f ? bf2f(((const u16*)lamsrc)[threadIdx.x])
                    : ((const float*)lamsrc)[threadIdx.x];
        lamf[threadIdx.x] = 1.0f / (1.0f + __expf(-v));
    }
}

// ---------------------------------------------------------------------------
// Fused QKV(+V-transpose) projection GEMM, inline dtype convert, round-2
// loop structure (NO register prefetch -- it spilled in round 3).
// Tile 128x128xK64, 4 waves 2x2, wave 64x64 (4x4 subtiles).
// grid.x = 32 (4 weights x 8 n-tiles), grid.y = 16 (m-tiles).
// ---------------------------------------------------------------------------
__global__ __launch_bounds__(256) void qkv_gemm(
    const void* __restrict__ xs, const void* __restrict__ wq,
    const void* __restrict__ wk1, const void* __restrict__ wk2,
    const void* __restrict__ wv, const int* __restrict__ flag,
    u16* __restrict__ qd, u16* __restrict__ k1d, u16* __restrict__ k2d,
    u16* __restrict__ vtd) {
    __shared__ __align__(16) u16 As[128 * 72];
    __shared__ __align__(16) u16 Bs[128 * 72];

    const int f = *flag;
    const int nt = blockIdx.x;
    const int mt = blockIdx.y;
    const int w = nt >> 3;
    const int n0 = (nt & 7) * 128;
    const int m0 = mt * 128;
    const void* Bp = (w == 0) ? wq : (w == 1) ? wk1 : (w == 2) ? wk2 : wv;

    const int tid = threadIdx.x;
    const int lane = tid & 63, wave = tid >> 6;
    const int lr = lane & 15, quad = lane >> 4;
    const int wm = (wave >> 1) * 64, wn = (wave & 1) * 64;

    f32x4 acc[4][4];
#pragma unroll
    for (int i = 0; i < 4; i++)
#pragma unroll
        for (int j = 0; j < 4; j++) acc[i][j] = (f32x4){0.f, 0.f, 0.f, 0.f};

    for (int k0 = 0; k0 < DM; k0 += 64) {
        __syncthreads();
#pragma unroll
        for (int it = 0; it < 4; it++) {
            int c = it * 256 + tid;
            int row = c >> 3, col = (c & 7) * 8;
            *(uint4*)(&As[row * 72 + col]) = ld8(xs, (size_t)(m0 + row) * DM + k0 + col, f);
            *(uint4*)(&Bs[row * 72 + col]) = ld8(Bp, (size_t)(n0 + row) * DM + k0 + col, f);
        }
        __syncthreads();
#pragma unroll
        for (int kk = 0; kk < 64; kk += 32) {
            bf16x8 af[4], bfr[4];
#pragma unroll
            for (int i = 0; i < 4; i++)
                af[i] = *(const bf16x8*)(&As[(wm + i * 16 + lr) * 72 + kk + quad * 8]);
#pragma unroll
            for (int j = 0; j < 4; j++)
                bfr[j] = *(const bf16x8*)(&Bs[(wn + j * 16 + lr) * 72 + kk + quad * 8]);
#pragma unroll
            for (int i = 0; i < 4; i++)
#pragma unroll
                for (int j = 0; j < 4; j++) acc[i][j] = mfma16(af[i], bfr[j], acc[i][j]);
        }
    }

#pragma unroll
    for (int i = 0; i < 4; i++)
#pragma unroll
        for (int j = 0; j < 4; j++)
#pragma unroll
            for (int r = 0; r < 4; r++) {
                int t = m0 + wm + i * 16 + quad * 4 + r;
                int o = n0 + wn + j * 16 + lr;
                u16 vbits = f2bf(acc[i][j][r]);
                int hh = o >> 6, d0 = o & 63;
                if (w == 3)
                    vtd[((size_t)hh * HD + d0) * T_SEQ + t] = vbits;   // v transposed
                else
                    ((w == 0) ? qd : (w == 1) ? k1d : k2d)[((size_t)hh * T_SEQ + t) * HD + d0] = vbits;
            }
}

// ---------------------------------------------------------------------------
// Two-pass max-free differential flash attention -- round-2 structure
// (LDS staging for Q/K1/K2/V, no register prefetch), plus diagonal-only
// masking (uniform branch; 32 of 33 tiles skip the per-element compares).
// Grid 512: h = b&15, i = b>>4, qt = i<16 ? i : 47-i (CU-pair balance).
// ---------------------------------------------------------------------------
__global__ __launch_bounds__(256) void attn_kernel(
    const u16* __restrict__ qg, const u16* __restrict__ k1g,
    const u16* __restrict__ k2g, const u16* __restrict__ vtg,
    const float* __restrict__ lamf, u16* __restrict__ ao) {
    __shared__ __align__(16) u16 qs[64 * LS];
    __shared__ __align__(16) u16 k1s[64 * LS];
    __shared__ __align__(16) u16 k2s[64 * LS];
    __shared__ __align__(16) u16 vs[64 * LS];
    __shared__ __align__(16) u16 ps[4][16 * LS];

    const int b = blockIdx.x;
    const int h = b & 15;
    const int bi = b >> 4;
    const int qt = (bi < 16) ? bi : 47 - bi;
    const int t0 = qt * 64;
    const int tid = threadIdx.x;
    const int lane = tid & 63, wave = tid >> 6;
    const int lr = lane & 15, quad = lane >> 4;
    const int wm = wave * 16;
    const float lam = lamf[h];

    const u16* qh = qg + (size_t)h * T_SEQ * HD;
    const u16* k1h = k1g + (size_t)h * T_SEQ * HD;
    const u16* k2h = k2g + (size_t)h * T_SEQ * HD;
    const u16* vh = vtg + (size_t)h * HD * T_SEQ;

    // stage q tile (64x64)
#pragma unroll
    for (int it = 0; it < 2; it++) {
        int c = it * 256 + tid;
        int row = c >> 3, col = (c & 7) * 8;
        *(uint4*)(&qs[row * LS + col]) = *(const uint4*)(&qh[(size_t)(t0 + row) * HD + col]);
    }

    const int nkt = qt + 1;

    // ---------------- pass A: per-lane Z accumulation ----------------
    float z1a[4] = {0.f, 0.f, 0.f, 0.f}, z2a[4] = {0.f, 0.f, 0.f, 0.f};

    for (int kt = 0; kt < nkt; kt++) {
        __syncthreads();
#pragma unroll
        for (int it = 0; it < 2; it++) {
            int c = it * 256 + tid;
            int row = c >> 3, col = (c & 7) * 8;
            *(uint4*)(&k1s[row * LS + col]) =
                *(const uint4*)(&k1h[(size_t)(kt * 64 + row) * HD + col]);
            *(uint4*)(&k2s[row * LS + col]) =
                *(const uint4*)(&k2h[(size_t)(kt * 64 + row) * HD + col]);
        }
        __syncthreads();

        f32x4 sa[4], sb[4];
#pragma unroll
        for (int j = 0; j < 4; j++) { sa[j] = (f32x4){0.f,0.f,0.f,0.f}; sb[j] = (f32x4){0.f,0.f,0.f,0.f}; }
#pragma unroll
        for (int kk = 0; kk < 64; kk += 32) {
            bf16x8 af = *(const bf16x8*)(&qs[(wm + lr) * LS + kk + quad * 8]);
            bf16x8 b1[4], b2[4];
#pragma unroll
            for (int j = 0; j < 4; j++) {
                b1[j] = *(const bf16x8*)(&k1s[(j * 16 + lr) * LS + kk + quad * 8]);
                b2[j] = *(const bf16x8*)(&k2s[(j * 16 + lr) * LS + kk + quad * 8]);
            }
#pragma unroll
            for (int j = 0; j < 4; j++) { sa[j] = mfma16(af, b1[j], sa[j]); sb[j] = mfma16(af, b2[j], sb[j]); }
        }

        if (kt < qt) {   // fully unmasked tile
#pragma unroll
            for (int r = 0; r < 4; r++)
#pragma unroll
                for (int j = 0; j < 4; j++) {
                    z1a[r] += ex2(sa[j][r] * SC2);
                    z2a[r] += ex2(sb[j][r] * SC2);
                }
        } else {          // diagonal tile
#pragma unroll
            for (int r = 0; r < 4; r++) {
                const int grow = t0 + wm + quad * 4 + r;
#pragma unroll
                for (int j = 0; j < 4; j++) {
                    int gcol = kt * 64 + j * 16 + lr;
                    if (gcol <= grow) {
                        z1a[r] += ex2(sa[j][r] * SC2);
                        z2a[r] += ex2(sb[j][r] * SC2);
                    }
                }
            }
        }
    }

    float z1i[4], z2i[4];
#pragma unroll
    for (int r = 0; r < 4; r++) {
        z1i[r] = 1.f / qsum16(z1a[r]);
        z2i[r] = lam / qsum16(z2a[r]);
    }

    f32x4 oac[4];
#pragma unroll
    for (int j = 0; j < 4; j++) oac[j] = (f32x4){0.f, 0.f, 0.f, 0.f};
    float dacc[4] = {0.f, 0.f, 0.f, 0.f};

    // ---------------- pass B: P, per-lane denom, PV ----------------
    for (int kt = 0; kt < nkt; kt++) {
        __syncthreads();
#pragma unroll
        for (int it = 0; it < 2; it++) {
            int c = it * 256 + tid;
            int row = c >> 3, col = (c & 7) * 8;
            *(uint4*)(&k1s[row * LS + col]) =
                *(const uint4*)(&k1h[(size_t)(kt * 64 + row) * HD + col]);
            *(uint4*)(&k2s[row * LS + col]) =
                *(const uint4*)(&k2h[(size_t)(kt * 64 + row) * HD + col]);
            *(uint4*)(&vs[row * LS + col]) =
                *(const uint4*)(&vh[(size_t)row * T_SEQ + kt * 64 + col]);
        }
        __syncthreads();

        f32x4 sa[4], sb[4];
#pragma unroll
        for (int j = 0; j < 4; j++) { sa[j] = (f32x4){0.f,0.f,0.f,0.f}; sb[j] = (f32x4){0.f,0.f,0.f,0.f}; }
#pragma unroll
        for (int kk = 0; kk < 64; kk += 32) {
            bf16x8 af = *(const bf16x8*)(&qs[(wm + lr) * LS + kk + quad * 8]);
            bf16x8 b1[4], b2[4];
#pragma unroll
            for (int j = 0; j < 4; j++) {
                b1[j] = *(const bf16x8*)(&k1s[(j * 16 + lr) * LS + kk + quad * 8]);
                b2[j] = *(const bf16x8*)(&k2s[(j * 16 + lr) * LS + kk + quad * 8]);
            }
#pragma unroll
            for (int j = 0; j < 4; j++) { sa[j] = mfma16(af, b1[j], sa[j]); sb[j] = mfma16(af, b2[j], sb[j]); }
        }

        if (kt < qt) {
#pragma unroll
            for (int r = 0; r < 4; r++)
#pragma unroll
                for (int j = 0; j < 4; j++) {
                    float p = ex2(sa[j][r] * SC2) * z1i[r] - ex2(sb[j][r] * SC2) * z2i[r];
                    dacc[r] += fabsf(p);
                    ps[wave][(quad * 4 + r) * LS + j * 16 + lr] = f2bf(p);
                }
        } else {
#pragma unroll
            for (int r = 0; r < 4; r++) {
                const int grow = t0 + wm + quad * 4 + r;
#pragma unroll
                for (int j = 0; j < 4; j++) {
                    int gcol = kt * 64 + j * 16 + lr;
                    float p = 0.f;
                    if (gcol <= grow)
                        p = ex2(sa[j][r] * SC2) * z1i[r] - ex2(sb[j][r] * SC2) * z2i[r];
                    dacc[r] += fabsf(p);
                    ps[wave][(quad * 4 + r) * LS + j * 16 + lr] = f2bf(p);
                }
            }
        }

        // PV: wave-local LDS round trip (DS pipe in-order per wave)
#pragma unroll
        for (int kk = 0; kk < 64; kk += 32) {
            bf16x8 pa = *(const bf16x8*)(&ps[wave][lr * LS + kk + quad * 8]);
            bf16x8 vb[4];
#pragma unroll
            for (int j = 0; j < 4; j++)
                vb[j] = *(const bf16x8*)(&vs[(j * 16 + lr) * LS + kk + quad * 8]);
#pragma unroll
            for (int j = 0; j < 4; j++) oac[j] = mfma16(pa, vb[j], oac[j]);
        }
    }

    float dnm[4];
#pragma unroll
    for (int r = 0; r < 4; r++) dnm[r] = 1.f / fmaxf(qsum16(dacc[r]), 1e-6f);
#pragma unroll
    for (int j = 0; j < 4; j++)
#pragma unroll
        for (int r = 0; r < 4; r++) {
            int rowl = wm + quad * 4 + r;
            float val = oac[j][r] * dnm[r];
            ao[(size_t)(t0 + rowl) * DM + h * HD + j * 16 + lr] = f2bf(val);
        }
}

// ---------------------------------------------------------------------------
// Output GEMM: out = ao @ Wo^T. 128x64 tiles -> 256 blocks, round-2 loop
// structure (no prefetch), inline Wo convert. Wave: 64x32 (4x2 subtiles).
// ---------------------------------------------------------------------------
__global__ __launch_bounds__(256) void out_gemm(
    const u16* __restrict__ ab, const void* __restrict__ wo,
    const int* __restrict__ flag, void* __restrict__ outp) {
    __shared__ __align__(16) u16 As[128 * 72];
    __shared__ __align__(16) u16 Bs[64 * 72];

    const int f = *flag;
    const int n0 = blockIdx.x * 64;    // 0..15
    const int m0 = blockIdx.y * 128;   // 0..15
    const int tid = threadIdx.x;
    const int lane = tid & 63, wave = tid >> 6;
    const int lr = lane & 15, quad = lane >> 4;
    const int wm = (wave >> 1) * 64, wn = (wave & 1) * 32;
    const int srow = tid >> 3, scol = (tid & 7) * 8;

    f32x4 acc[4][2];
#pragma unroll
    for (int i = 0; i < 4; i++)
#pragma unroll
        for (int j = 0; j < 2; j++) acc[i][j] = (f32x4){0.f, 0.f, 0.f, 0.f};

    for (int k0 = 0; k0 < DM; k0 += 64) {
        __syncthreads();
#pragma unroll
        for (int it = 0; it < 4; it++)
            *(uint4*)(&As[(it * 32 + srow) * 72 + scol]) =
                *(const uint4*)(&ab[(size_t)(m0 + it * 32 + srow) * DM + k0 + scol]);
#pragma unroll
        for (int it = 0; it < 2; it++)
            *(uint4*)(&Bs[(it * 32 + srow) * 72 + scol]) =
                ld8(wo, (size_t)(n0 + it * 32 + srow) * DM + k0 + scol, f);
        __syncthreads();
#pragma unroll
        for (int kk = 0; kk < 64; kk += 32) {
            bf16x8 af[4], bfr[2];
#pragma unroll
            for (int i = 0; i < 4; i++)
                af[i] = *(const bf16x8*)(&As[(wm + i * 16 + lr) * 72 + kk + quad * 8]);
#pragma unroll
            for (int j = 0; j < 2; j++)
                bfr[j] = *(const bf16x8*)(&Bs[(wn + j * 16 + lr) * 72 + kk + quad * 8]);
#pragma unroll
            for (int i = 0; i < 4; i++)
#pragma unroll
                for (int j = 0; j < 2; j++) acc[i][j] = mfma16(af[i], bfr[j], acc[i][j]);
        }
    }

#pragma unroll
    for (int i = 0; i < 4; i++)
#pragma unroll
        for (int j = 0; j < 2; j++)
#pragma unroll
            for (int r = 0; r < 4; r++) {
                int t = m0 + wm + i * 16 + quad * 4 + r;
                int o = n0 + wn + j * 16 + lr;
                float val = acc[i][j][r];
                if (f)
                    ((u16*)outp)[(size_t)t * DM + o] = f2bf(val);
                else
                    ((float*)outp)[(size_t)t * DM + o] = val;
            }
}

extern "C" void kernel_launch(void* const* d_in, const int* in_sizes, int n_in,
                              void* d_out, int out_size, void* d_ws, size_t ws_size,
                              hipStream_t stream) {
    char* ws = (char*)d_ws;
    int* flag = (int*)(ws + 0);
    float* lamf = (float*)(ws + 256);
    u16* qd  = (u16*)(ws + ((size_t)16 << 20));  // [H][T][64]
    u16* k1d = (u16*)(ws + ((size_t)20 << 20));
    u16* k2d = (u16*)(ws + ((size_t)24 << 20));
    u16* vtd = (u16*)(ws + ((size_t)28 << 20));  // [H][64][T]
    u16* ao  = (u16*)(ws + ((size_t)32 << 20));  // [T][DM]

    detect_lam<<<1, 256, 0, stream>>>((const u16*)d_in[0], d_in[6], flag, lamf);
    qkv_gemm<<<dim3(32, 16), 256, 0, stream>>>(d_in[0], d_in[1], d_in[2], d_in[3],
                                               d_in[4], flag, qd, k1d, k2d, vtd);
    attn_kernel<<<dim3(512), 256, 0, stream>>>(qd, k1d, k2d, vtd, lamf, ao);
    out_gemm<<<dim3(16, 16), 256, 0, stream>>>(ao, d_in[5], flag, d_out);
}

// Round 5
// 231.355 us; speedup vs baseline: 1.3925x; 1.1269x over previous
//
#include <hip/hip_runtime.h>

#define T_SEQ 2048
#define DM 1024
#define NH 16
#define HD 64
// SCALE * log2(e) : softmax computed in exp2 domain
#define SC2 0.1803368801111731f
#define LS 80   // ps LDS row stride (u16)

typedef unsigned short u16;
typedef unsigned int u32;
typedef __attribute__((ext_vector_type(8))) short bf16x8;
typedef __attribute__((ext_vector_type(4))) float f32x4;

static __device__ __forceinline__ f32x4 mfma16(bf16x8 a, bf16x8 b, f32x4 c) {
    return __builtin_amdgcn_mfma_f32_16x16x32_bf16(a, b, c, 0, 0, 0);
}
static __device__ __forceinline__ float bf2f(u16 u) {
    union { u32 i; float f; } v; v.i = ((u32)u) << 16; return v.f;
}
static __device__ __forceinline__ u16 f2bf(float f) {
    union { float f; u32 i; } v; v.f = f;
    u32 x = v.i;
    x += 0x7FFFu + ((x >> 16) & 1u);   // RNE
    return (u16)(x >> 16);
}
static __device__ __forceinline__ u32 pk2(float lo, float hi) {
    return (u32)f2bf(lo) | ((u32)f2bf(hi) << 16);
}
// load 8 contiguous elements as packed bf16; converts from f32 if f==0.
static __device__ __forceinline__ uint4 ld8(const void* src, size_t idx, int f) {
    if (f) return *(const uint4*)((const u16*)src + idx);
    const float* s = (const float*)src + idx;
    uint4 a = *(const uint4*)s;
    uint4 b = *(const uint4*)(s + 4);
    const float* af = (const float*)&a;
    const float* bf = (const float*)&b;
    uint4 r;
    r.x = pk2(af[0], af[1]); r.y = pk2(af[2], af[3]);
    r.z = pk2(bf[0], bf[1]); r.w = pk2(bf[2], bf[3]);
    return r;
}
static __device__ __forceinline__ float qsum16(float v) {
#pragma unroll
    for (int o = 1; o < 16; o <<= 1) v += __shfl_xor(v, o, 64);
    return v;
}
static __device__ __forceinline__ float ex2(float x) {
    return __builtin_amdgcn_exp2f(x);
}

// Async global->LDS DMA, 16 B per lane. LDS dest is wave-uniform base +
// lane*16 (lane0's pointer is the base; our mapping makes them consistent).
static __device__ __forceinline__ void gl16(const u16* g, u16* l) {
    __builtin_amdgcn_global_load_lds(
        (const __attribute__((address_space(1))) void*)g,
        (__attribute__((address_space(3))) void*)l,
        16, 0, 0);
}

// ---------------------------------------------------------------------------
// Tile staging into unpadded LDS (row stride 64 u16 = 128 B) with XOR chunk
// swizzle: LDS slot (r, cs) holds global chunk cs^(r&7). Global side stays
// fully coalesced (permutation within each 128 B segment); LDS b128 fragment
// reads become 2-way conflicts (free).  NISS = nrows/32 for 256 threads.
// ---------------------------------------------------------------------------
template <int NISS>
static __device__ __forceinline__ void stage_async(const u16* src, size_t row0,
                                                   size_t lds_, size_t col0,
                                                   u16* dst, int tid) {
#pragma unroll
    for (int it = 0; it < NISS; it++) {
        int r = it * 32 + (tid >> 3);
        int cg = (tid & 7) ^ (r & 7);
        gl16(&src[(row0 + r) * lds_ + col0 + cg * 8], &dst[(it * 256 + tid) * 8]);
    }
}
template <int NISS>
static __device__ __forceinline__ void stage_sync(const void* src, size_t row0,
                                                  size_t lds_, size_t col0,
                                                  u16* dst, int tid, int f) {
#pragma unroll
    for (int it = 0; it < NISS; it++) {
        int r = it * 32 + (tid >> 3);
        int cg = (tid & 7) ^ (r & 7);
        *(uint4*)(&dst[(it * 256 + tid) * 8]) =
            ld8(src, (row0 + r) * lds_ + col0 + cg * 8, f);
    }
}
// fragment read from a swizzled tile: row R, kk in {0,1} (u16 col = kk*32+quad*8)
static __device__ __forceinline__ bf16x8 frag(const u16* buf, int R, int co) {
    return *(const bf16x8*)(&buf[R * 64 + co]);
}

// ---------------------------------------------------------------------------
// dtype detection + lambda.
// ---------------------------------------------------------------------------
__global__ void detect_lam(const u16* __restrict__ x, const void* __restrict__ lamsrc,
                           int* __restrict__ flag, float* __restrict__ lamf) {
    __shared__ int tot;
    if (threadIdx.x == 0) tot = 0;
    __syncthreads();
    int c = 0;
    for (int i = threadIdx.x; i < 1024; i += 256) {
        u16 v = x[2 * i];
        int e = (v >> 7) & 0xFF;
        c += (e >= 110 && e <= 140) ? 1 : 0;
    }
    atomicAdd(&tot, c);
    __syncthreads();
    const int f = (tot >= 512) ? 1 : 0;
    if (threadIdx.x == 0) *flag = f;
    if (threadIdx.x < NH) {
        float v = f ? bf2f(((const u16*)lamsrc)[threadIdx.x])
                    : ((const float*)lamsrc)[threadIdx.x];
        lamf[threadIdx.x] = 1.0f / (1.0f + __expf(-v));
    }
}

// ---------------------------------------------------------------------------
// QKV(+V-transpose) projection GEMM. Tile 128x64xK64, async DMA staging,
// double-buffered LDS, one barrier per K-iter. grid(64,16):
// x = w*16 + n-tile (n0 = nt*64), y = m-tile (m0 = y*128). 1024 blocks.
// 4 waves 2x2: wave covers 64x32 (acc[4][2]).
// ---------------------------------------------------------------------------
__global__ __launch_bounds__(256) void qkv_gemm(
    const void* __restrict__ xs, const void* __restrict__ wq,
    const void* __restrict__ wk1, const void* __restrict__ wk2,
    const void* __restrict__ wv, const int* __restrict__ flag,
    u16* __restrict__ qd, u16* __restrict__ k1d, u16* __restrict__ k2d,
    u16* __restrict__ vtd) {
    __shared__ __align__(16) u16 As[2][128 * 64];
    __shared__ __align__(16) u16 Bs[2][64 * 64];

    const int f = *flag;
    const int w = blockIdx.x >> 4;
    const int n0 = (blockIdx.x & 15) * 64;
    const int m0 = blockIdx.y * 128;
    const void* Bpv = (w == 0) ? wq : (w == 1) ? wk1 : (w == 2) ? wk2 : wv;
    const u16* xb = (const u16*)xs;
    const u16* Bb = (const u16*)Bpv;

    const int tid = threadIdx.x;
    const int lane = tid & 63, wave = tid >> 6;
    const int lr = lane & 15, quad = lane >> 4;
    const int wm = (wave >> 1) * 64, wn = (wave & 1) * 32;
    const int sw = lr & 7;   // fragment-read swizzle key (R&7 == lr&7 here)

    f32x4 acc[4][2];
#pragma unroll
    for (int i = 0; i < 4; i++)
#pragma unroll
        for (int j = 0; j < 2; j++) acc[i][j] = (f32x4){0.f, 0.f, 0.f, 0.f};

    if (f) {
        stage_async<4>(xb, m0, DM, 0, As[0], tid);
        stage_async<2>(Bb, n0, DM, 0, Bs[0], tid);
    }
    for (int k0 = 0; k0 < DM; k0 += 64) {
        const int cur = (k0 >> 6) & 1;
        __syncthreads();
        if (f) {
            if (k0 + 64 < DM) {
                stage_async<4>(xb, m0, DM, k0 + 64, As[cur ^ 1], tid);
                stage_async<2>(Bb, n0, DM, k0 + 64, Bs[cur ^ 1], tid);
            }
        } else {
            stage_sync<4>(xs, m0, DM, k0, As[cur], tid, 0);
            stage_sync<2>(Bpv, n0, DM, k0, Bs[cur], tid, 0);
            __syncthreads();
        }
#pragma unroll
        for (int kk = 0; kk < 2; kk++) {
            const int co = ((kk * 4 + quad) ^ sw) * 8;
            bf16x8 af[4], bfr[2];
#pragma unroll
            for (int i = 0; i < 4; i++) af[i] = frag(As[cur], wm + i * 16 + lr, co);
#pragma unroll
            for (int j = 0; j < 2; j++) bfr[j] = frag(Bs[cur], wn + j * 16 + lr, co);
#pragma unroll
            for (int i = 0; i < 4; i++)
#pragma unroll
                for (int j = 0; j < 2; j++) acc[i][j] = mfma16(af[i], bfr[j], acc[i][j]);
        }
    }

#pragma unroll
    for (int i = 0; i < 4; i++)
#pragma unroll
        for (int j = 0; j < 2; j++)
#pragma unroll
            for (int r = 0; r < 4; r++) {
                int t = m0 + wm + i * 16 + quad * 4 + r;
                int o = n0 + wn + j * 16 + lr;
                u16 vbits = f2bf(acc[i][j][r]);
                int hh = o >> 6, d0 = o & 63;
                if (w == 3)
                    vtd[((size_t)hh * HD + d0) * T_SEQ + t] = vbits;   // v transposed
                else
                    ((w == 0) ? qd : (w == 1) ? k1d : k2d)[((size_t)hh * T_SEQ + t) * HD + d0] = vbits;
            }
}

// ---------------------------------------------------------------------------
// Two-pass max-free differential flash attention, async DMA dbuf staging for
// K1/K2/V (one barrier per tile), Q direct global->registers (8 VGPRs).
// Grid 512: h = b&15, i = b>>4, qt = i<16 ? i : 47-i (CU-pair balance).
// ---------------------------------------------------------------------------
__global__ __launch_bounds__(256) void attn_kernel(
    const u16* __restrict__ qg, const u16* __restrict__ k1g,
    const u16* __restrict__ k2g, const u16* __restrict__ vtg,
    const float* __restrict__ lamf, u16* __restrict__ ao) {
    __shared__ __align__(16) u16 k1s[2][64 * 64];
    __shared__ __align__(16) u16 k2s[2][64 * 64];
    __shared__ __align__(16) u16 vs[2][64 * 64];
    __shared__ __align__(16) u16 ps[4][16 * LS];

    const int b = blockIdx.x;
    const int h = b & 15;
    const int bi = b >> 4;
    const int qt = (bi < 16) ? bi : 47 - bi;
    const int t0 = qt * 64;
    const int tid = threadIdx.x;
    const int lane = tid & 63, wave = tid >> 6;
    const int lr = lane & 15, quad = lane >> 4;
    const int wm = wave * 16;
    const float lam = lamf[h];
    const int sw = lr & 7;

    const u16* qh = qg + (size_t)h * T_SEQ * HD;
    const u16* k1h = k1g + (size_t)h * T_SEQ * HD;
    const u16* k2h = k2g + (size_t)h * T_SEQ * HD;
    const u16* vh = vtg + (size_t)h * HD * T_SEQ;

    // Q A-fragments straight from global: row t0+wm+lr, cols kk*32+quad*8
    bf16x8 aq[2];
#pragma unroll
    for (int kk = 0; kk < 2; kk++)
        aq[kk] = *(const bf16x8*)(&qh[(size_t)(t0 + wm + lr) * HD + kk * 32 + quad * 8]);

    const int nkt = qt + 1;

    // prefetch K tile 0
    stage_async<2>(k1h, 0, HD, 0, k1s[0], tid);
    stage_async<2>(k2h, 0, HD, 0, k2s[0], tid);

    // ---------------- pass A: per-lane Z accumulation ----------------
    float z1a[4] = {0.f, 0.f, 0.f, 0.f}, z2a[4] = {0.f, 0.f, 0.f, 0.f};

    for (int kt = 0; kt < nkt; kt++) {
        const int cur = kt & 1;
        __syncthreads();
        if (kt + 1 < nkt) {
            stage_async<2>(k1h, (size_t)(kt + 1) * 64, HD, 0, k1s[cur ^ 1], tid);
            stage_async<2>(k2h, (size_t)(kt + 1) * 64, HD, 0, k2s[cur ^ 1], tid);
        }

        f32x4 sa[4], sb[4];
#pragma unroll
        for (int j = 0; j < 4; j++) { sa[j] = (f32x4){0.f,0.f,0.f,0.f}; sb[j] = (f32x4){0.f,0.f,0.f,0.f}; }
#pragma unroll
        for (int kk = 0; kk < 2; kk++) {
            const int co = ((kk * 4 + quad) ^ sw) * 8;
#pragma unroll
            for (int j = 0; j < 4; j++) {
                bf16x8 b1 = frag(k1s[cur], j * 16 + lr, co);
                bf16x8 b2 = frag(k2s[cur], j * 16 + lr, co);
                sa[j] = mfma16(aq[kk], b1, sa[j]);
                sb[j] = mfma16(aq[kk], b2, sb[j]);
            }
        }

        if (kt < qt) {   // fully unmasked tile
#pragma unroll
            for (int r = 0; r < 4; r++)
#pragma unroll
                for (int j = 0; j < 4; j++) {
                    z1a[r] += ex2(sa[j][r] * SC2);
                    z2a[r] += ex2(sb[j][r] * SC2);
                }
        } else {          // diagonal tile
#pragma unroll
            for (int r = 0; r < 4; r++) {
                const int grow = t0 + wm + quad * 4 + r;
#pragma unroll
                for (int j = 0; j < 4; j++) {
                    int gcol = kt * 64 + j * 16 + lr;
                    if (gcol <= grow) {
                        z1a[r] += ex2(sa[j][r] * SC2);
                        z2a[r] += ex2(sb[j][r] * SC2);
                    }
                }
            }
        }
    }

    float z1i[4], z2i[4];
#pragma unroll
    for (int r = 0; r < 4; r++) {
        z1i[r] = 1.f / qsum16(z1a[r]);
        z2i[r] = lam / qsum16(z2a[r]);
    }

    f32x4 oac[4];
#pragma unroll
    for (int j = 0; j < 4; j++) oac[j] = (f32x4){0.f, 0.f, 0.f, 0.f};
    float dacc[4] = {0.f, 0.f, 0.f, 0.f};

    // protect pass-A's last reads, then prefetch pass-B tile 0
    __syncthreads();
    stage_async<2>(k1h, 0, HD, 0, k1s[0], tid);
    stage_async<2>(k2h, 0, HD, 0, k2s[0], tid);
    stage_async<2>(vh, 0, T_SEQ, 0, vs[0], tid);

    // ---------------- pass B: P, per-lane denom, PV ----------------
    for (int kt = 0; kt < nkt; kt++) {
        const int cur = kt & 1;
        __syncthreads();
        if (kt + 1 < nkt) {
            stage_async<2>(k1h, (size_t)(kt + 1) * 64, HD, 0, k1s[cur ^ 1], tid);
            stage_async<2>(k2h, (size_t)(kt + 1) * 64, HD, 0, k2s[cur ^ 1], tid);
            stage_async<2>(vh, 0, T_SEQ, (size_t)(kt + 1) * 64, vs[cur ^ 1], tid);
        }

        f32x4 sa[4], sb[4];
#pragma unroll
        for (int j = 0; j < 4; j++) { sa[j] = (f32x4){0.f,0.f,0.f,0.f}; sb[j] = (f32x4){0.f,0.f,0.f,0.f}; }
#pragma unroll
        for (int kk = 0; kk < 2; kk++) {
            const int co = ((kk * 4 + quad) ^ sw) * 8;
#pragma unroll
            for (int j = 0; j < 4; j++) {
                bf16x8 b1 = frag(k1s[cur], j * 16 + lr, co);
                bf16x8 b2 = frag(k2s[cur], j * 16 + lr, co);
                sa[j] = mfma16(aq[kk], b1, sa[j]);
                sb[j] = mfma16(aq[kk], b2, sb[j]);
            }
        }

        if (kt < qt) {
#pragma unroll
            for (int r = 0; r < 4; r++)
#pragma unroll
                for (int j = 0; j < 4; j++) {
                    float p = ex2(sa[j][r] * SC2) * z1i[r] - ex2(sb[j][r] * SC2) * z2i[r];
                    dacc[r] += fabsf(p);
                    ps[wave][(quad * 4 + r) * LS + j * 16 + lr] = f2bf(p);
                }
        } else {
#pragma unroll
            for (int r = 0; r < 4; r++) {
                const int grow = t0 + wm + quad * 4 + r;
#pragma unroll
                for (int j = 0; j < 4; j++) {
                    int gcol = kt * 64 + j * 16 + lr;
                    float p = 0.f;
                    if (gcol <= grow)
                        p = ex2(sa[j][r] * SC2) * z1i[r] - ex2(sb[j][r] * SC2) * z2i[r];
                    dacc[r] += fabsf(p);
                    ps[wave][(quad * 4 + r) * LS + j * 16 + lr] = f2bf(p);
                }
            }
        }

        // PV: wave-local LDS round trip (DS pipe in-order per wave)
#pragma unroll
        for (int kk = 0; kk < 2; kk++) {
            bf16x8 pa = *(const bf16x8*)(&ps[wave][lr * LS + kk * 32 + quad * 8]);
            const int co = ((kk * 4 + quad) ^ sw) * 8;
#pragma unroll
            for (int j = 0; j < 4; j++) {
                bf16x8 vb = frag(vs[cur], j * 16 + lr, co);
                oac[j] = mfma16(pa, vb, oac[j]);
            }
        }
    }

    float dnm[4];
#pragma unroll
    for (int r = 0; r < 4; r++) dnm[r] = 1.f / fmaxf(qsum16(dacc[r]), 1e-6f);
#pragma unroll
    for (int j = 0; j < 4; j++)
#pragma unroll
        for (int r = 0; r < 4; r++) {
            int rowl = wm + quad * 4 + r;
            float val = oac[j][r] * dnm[r];
            ao[(size_t)(t0 + rowl) * DM + h * HD + j * 16 + lr] = f2bf(val);
        }
}

// ---------------------------------------------------------------------------
// Output GEMM: out = ao @ Wo^T. Tile 128x64, async dbuf staging (A always
// bf16 ws; B dual-path), 256 blocks. Wave covers 64x32 (acc[4][2]).
// ---------------------------------------------------------------------------
__global__ __launch_bounds__(256) void out_gemm(
    const u16* __restrict__ ab, const void* __restrict__ wo,
    const int* __restrict__ flag, void* __restrict__ outp) {
    __shared__ __align__(16) u16 As[2][128 * 64];
    __shared__ __align__(16) u16 Bs[2][64 * 64];

    const int f = *flag;
    const int n0 = blockIdx.x * 64;    // 0..15
    const int m0 = blockIdx.y * 128;   // 0..15
    const u16* wb = (const u16*)wo;
    const int tid = threadIdx.x;
    const int lane = tid & 63, wave = tid >> 6;
    const int lr = lane & 15, quad = lane >> 4;
    const int wm = (wave >> 1) * 64, wn = (wave & 1) * 32;
    const int sw = lr & 7;

    f32x4 acc[4][2];
#pragma unroll
    for (int i = 0; i < 4; i++)
#pragma unroll
        for (int j = 0; j < 2; j++) acc[i][j] = (f32x4){0.f, 0.f, 0.f, 0.f};

    if (f) {
        stage_async<4>(ab, m0, DM, 0, As[0], tid);
        stage_async<2>(wb, n0, DM, 0, Bs[0], tid);
    }
    for (int k0 = 0; k0 < DM; k0 += 64) {
        const int cur = (k0 >> 6) & 1;
        __syncthreads();
        if (f) {
            if (k0 + 64 < DM) {
                stage_async<4>(ab, m0, DM, k0 + 64, As[cur ^ 1], tid);
                stage_async<2>(wb, n0, DM, k0 + 64, Bs[cur ^ 1], tid);
            }
        } else {
            stage_sync<4>(ab, m0, DM, k0, As[cur], tid, 1);
            stage_sync<2>(wo, n0, DM, k0, Bs[cur], tid, 0);
            __syncthreads();
        }
#pragma unroll
        for (int kk = 0; kk < 2; kk++) {
            const int co = ((kk * 4 + quad) ^ sw) * 8;
            bf16x8 af[4], bfr[2];
#pragma unroll
            for (int i = 0; i < 4; i++) af[i] = frag(As[cur], wm + i * 16 + lr, co);
#pragma unroll
            for (int j = 0; j < 2; j++) bfr[j] = frag(Bs[cur], wn + j * 16 + lr, co);
#pragma unroll
            for (int i = 0; i < 4; i++)
#pragma unroll
                for (int j = 0; j < 2; j++) acc[i][j] = mfma16(af[i], bfr[j], acc[i][j]);
        }
    }

#pragma unroll
    for (int i = 0; i < 4; i++)
#pragma unroll
        for (int j = 0; j < 2; j++)
#pragma unroll
            for (int r = 0; r < 4; r++) {
                int t = m0 + wm + i * 16 + quad * 4 + r;
                int o = n0 + wn + j * 16 + lr;
                float val = acc[i][j][r];
                if (f)
                    ((u16*)outp)[(size_t)t * DM + o] = f2bf(val);
                else
                    ((float*)outp)[(size_t)t * DM + o] = val;
            }
}

extern "C" void kernel_launch(void* const* d_in, const int* in_sizes, int n_in,
                              void* d_out, int out_size, void* d_ws, size_t ws_size,
                              hipStream_t stream) {
    char* ws = (char*)d_ws;
    int* flag = (int*)(ws + 0);
    float* lamf = (float*)(ws + 256);
    u16* qd  = (u16*)(ws + ((size_t)16 << 20));  // [H][T][64]
    u16* k1d = (u16*)(ws + ((size_t)20 << 20));
    u16* k2d = (u16*)(ws + ((size_t)24 << 20));
    u16* vtd = (u16*)(ws + ((size_t)28 << 20));  // [H][64][T]
    u16* ao  = (u16*)(ws + ((size_t)32 << 20));  // [T][DM]

    detect_lam<<<1, 256, 0, stream>>>((const u16*)d_in[0], d_in[6], flag, lamf);
    qkv_gemm<<<dim3(64, 16), 256, 0, stream>>>(d_in[0], d_in[1], d_in[2], d_in[3],
                                               d_in[4], flag, qd, k1d, k2d, vtd);
    attn_kernel<<<dim3(512), 256, 0, stream>>>(qd, k1d, k2d, vtd, lamf, ao);
    out_gemm<<<dim3(16, 16), 256, 0, stream>>>(ao, d_in[5], flag, d_out);
}

// Round 6
// 225.040 us; speedup vs baseline: 1.4316x; 1.0281x over previous
//
#include <hip/hip_runtime.h>

#define T_SEQ 2048
#define DM 1024
#define NH 16
#define HD 64
// SCALE * log2(e) : softmax computed in exp2 domain (folded into Q in qkv_gemm)
#define SC2 0.1803368801111731f
#define LS 80   // ps LDS row stride (u16)

typedef unsigned short u16;
typedef unsigned int u32;
typedef __attribute__((ext_vector_type(8))) short bf16x8;
typedef __attribute__((ext_vector_type(4))) float f32x4;

static __device__ __forceinline__ f32x4 mfma16(bf16x8 a, bf16x8 b, f32x4 c) {
    return __builtin_amdgcn_mfma_f32_16x16x32_bf16(a, b, c, 0, 0, 0);
}
static __device__ __forceinline__ float bf2f(u16 u) {
    union { u32 i; float f; } v; v.i = ((u32)u) << 16; return v.f;
}
static __device__ __forceinline__ u16 f2bf(float f) {
    union { float f; u32 i; } v; v.f = f;
    u32 x = v.i;
    x += 0x7FFFu + ((x >> 16) & 1u);   // RNE
    return (u16)(x >> 16);
}
static __device__ __forceinline__ u16 f2bf_t(float f) {   // truncating (1 op)
    union { float f; u32 i; } v; v.f = f;
    return (u16)(v.i >> 16);
}
static __device__ __forceinline__ u32 pk2(float lo, float hi) {
    return (u32)f2bf(lo) | ((u32)f2bf(hi) << 16);
}
// load 8 contiguous elements as packed bf16; converts from f32 if f==0.
static __device__ __forceinline__ uint4 ld8(const void* src, size_t idx, int f) {
    if (f) return *(const uint4*)((const u16*)src + idx);
    const float* s = (const float*)src + idx;
    uint4 a = *(const uint4*)s;
    uint4 b = *(const uint4*)(s + 4);
    const float* af = (const float*)&a;
    const float* bf = (const float*)&b;
    uint4 r;
    r.x = pk2(af[0], af[1]); r.y = pk2(af[2], af[3]);
    r.z = pk2(bf[0], bf[1]); r.w = pk2(bf[2], bf[3]);
    return r;
}
static __device__ __forceinline__ float qsum16(float v) {
#pragma unroll
    for (int o = 1; o < 16; o <<= 1) v += __shfl_xor(v, o, 64);
    return v;
}
static __device__ __forceinline__ float ex2(float x) {
    return __builtin_amdgcn_exp2f(x);
}

// Async global->LDS DMA, 16 B per lane.
static __device__ __forceinline__ void gl16(const u16* g, u16* l) {
    __builtin_amdgcn_global_load_lds(
        (const __attribute__((address_space(1))) void*)g,
        (__attribute__((address_space(3))) void*)l,
        16, 0, 0);
}

// ---------------------------------------------------------------------------
// Staging into unpadded LDS (row stride 64 u16 = 128 B) with XOR chunk
// swizzle: LDS slot (r, c) holds global chunk c^(r&7). Global side fully
// coalesced; b128 fragment reads land 2-way (free).
// ---------------------------------------------------------------------------
template <int NISS>
static __device__ __forceinline__ void stage_async(const u16* src, size_t row0,
                                                   size_t lds_, size_t col0,
                                                   u16* dst, int tid) {
#pragma unroll
    for (int it = 0; it < NISS; it++) {
        int r = it * 32 + (tid >> 3);
        int cg = (tid & 7) ^ (r & 7);
        gl16(&src[(row0 + r) * lds_ + col0 + cg * 8], &dst[(it * 256 + tid) * 8]);
    }
}
template <int NISS>
static __device__ __forceinline__ void stage_sync(const void* src, size_t row0,
                                                  size_t lds_, size_t col0,
                                                  u16* dst, int tid, int f) {
#pragma unroll
    for (int it = 0; it < NISS; it++) {
        int r = it * 32 + (tid >> 3);
        int cg = (tid & 7) ^ (r & 7);
        *(uint4*)(&dst[(it * 256 + tid) * 8]) =
            ld8(src, (row0 + r) * lds_ + col0 + cg * 8, f);
    }
}
static __device__ __forceinline__ bf16x8 frag(const u16* buf, int R, int co) {
    return *(const bf16x8*)(&buf[R * 64 + co]);
}

// ---------------------------------------------------------------------------
// dtype detection + lambda.
// ---------------------------------------------------------------------------
__global__ void detect_lam(const u16* __restrict__ x, const void* __restrict__ lamsrc,
                           int* __restrict__ flag, float* __restrict__ lamf) {
    __shared__ int tot;
    if (threadIdx.x == 0) tot = 0;
    __syncthreads();
    int c = 0;
    for (int i = threadIdx.x; i < 1024; i += 256) {
        u16 v = x[2 * i];
        int e = (v >> 7) & 0xFF;
        c += (e >= 110 && e <= 140) ? 1 : 0;
    }
    atomicAdd(&tot, c);
    __syncthreads();
    const int f = (tot >= 512) ? 1 : 0;
    if (threadIdx.x == 0) *flag = f;
    if (threadIdx.x < NH) {
        float v = f ? bf2f(((const u16*)lamsrc)[threadIdx.x])
                    : ((const float*)lamsrc)[threadIdx.x];
        lamf[threadIdx.x] = 1.0f / (1.0f + __expf(-v));
    }
}

// ---------------------------------------------------------------------------
// QKV(+V-transpose) projection GEMM. Tile 128x64xK64, async DMA dbuf.
// Q output is PRE-SCALED by SC2 (softmax exp2-domain scale folded in).
// ---------------------------------------------------------------------------
__global__ __launch_bounds__(256) void qkv_gemm(
    const void* __restrict__ xs, const void* __restrict__ wq,
    const void* __restrict__ wk1, const void* __restrict__ wk2,
    const void* __restrict__ wv, const int* __restrict__ flag,
    u16* __restrict__ qd, u16* __restrict__ k1d, u16* __restrict__ k2d,
    u16* __restrict__ vtd) {
    __shared__ __align__(16) u16 As[2][128 * 64];
    __shared__ __align__(16) u16 Bs[2][64 * 64];

    const int f = *flag;
    const int w = blockIdx.x >> 4;
    const int n0 = (blockIdx.x & 15) * 64;
    const int m0 = blockIdx.y * 128;
    const void* Bpv = (w == 0) ? wq : (w == 1) ? wk1 : (w == 2) ? wk2 : wv;
    const u16* xb = (const u16*)xs;
    const u16* Bb = (const u16*)Bpv;

    const int tid = threadIdx.x;
    const int lane = tid & 63, wave = tid >> 6;
    const int lr = lane & 15, quad = lane >> 4;
    const int wm = (wave >> 1) * 64, wn = (wave & 1) * 32;
    const int sw = lr & 7;

    f32x4 acc[4][2];
#pragma unroll
    for (int i = 0; i < 4; i++)
#pragma unroll
        for (int j = 0; j < 2; j++) acc[i][j] = (f32x4){0.f, 0.f, 0.f, 0.f};

    if (f) {
        stage_async<4>(xb, m0, DM, 0, As[0], tid);
        stage_async<2>(Bb, n0, DM, 0, Bs[0], tid);
    }
    for (int k0 = 0; k0 < DM; k0 += 64) {
        const int cur = (k0 >> 6) & 1;
        __syncthreads();
        if (f) {
            if (k0 + 64 < DM) {
                stage_async<4>(xb, m0, DM, k0 + 64, As[cur ^ 1], tid);
                stage_async<2>(Bb, n0, DM, k0 + 64, Bs[cur ^ 1], tid);
            }
        } else {
            stage_sync<4>(xs, m0, DM, k0, As[cur], tid, 0);
            stage_sync<2>(Bpv, n0, DM, k0, Bs[cur], tid, 0);
            __syncthreads();
        }
#pragma unroll
        for (int kk = 0; kk < 2; kk++) {
            const int co = ((kk * 4 + quad) ^ sw) * 8;
            bf16x8 af[4], bfr[2];
#pragma unroll
            for (int i = 0; i < 4; i++) af[i] = frag(As[cur], wm + i * 16 + lr, co);
#pragma unroll
            for (int j = 0; j < 2; j++) bfr[j] = frag(Bs[cur], wn + j * 16 + lr, co);
#pragma unroll
            for (int i = 0; i < 4; i++)
#pragma unroll
                for (int j = 0; j < 2; j++) acc[i][j] = mfma16(af[i], bfr[j], acc[i][j]);
        }
    }

#pragma unroll
    for (int i = 0; i < 4; i++)
#pragma unroll
        for (int j = 0; j < 2; j++)
#pragma unroll
            for (int r = 0; r < 4; r++) {
                int t = m0 + wm + i * 16 + quad * 4 + r;
                int o = n0 + wn + j * 16 + lr;
                float val = acc[i][j][r];
                if (w == 0) val *= SC2;               // fold softmax scale into Q
                u16 vbits = f2bf(val);
                int hh = o >> 6, d0 = o & 63;
                if (w == 3)
                    vtd[((size_t)hh * HD + d0) * T_SEQ + t] = vbits;   // v transposed
                else
                    ((w == 0) ? qd : (w == 1) ? k1d : k2d)[((size_t)hh * T_SEQ + t) * HD + d0] = vbits;
            }
}

// ---------------------------------------------------------------------------
// Grid-1024 mapping shared by attn_a/attn_b: b -> (par, h, qt) such that CU c
// (blocks c, c+256, c+512, c+768) gets par0:{qt,31-qt} + par1:{qt,31-qt}
// -> ~33 k-tiles per CU regardless of c. Block processes strip kt ≡ par (2).
// ---------------------------------------------------------------------------
#define ATTN_MAP()                                            \
    const int b = blockIdx.x;                                 \
    const int par = b >> 9;                                   \
    const int rem = b & 511;                                  \
    const int h = rem & 15;                                   \
    const int bi = rem >> 4;                                  \
    const int qt = (bi < 16) ? bi : 47 - bi;                  \
    const int t0 = qt * 64;                                   \
    const int tid = threadIdx.x;                              \
    const int lane = tid & 63, wave = tid >> 6;               \
    const int lr = lane & 15, quad = lane >> 4;               \
    const int wm = wave * 16;                                 \
    const int sw = lr & 7;

// ---------------------------------------------------------------------------
// attn_a: partial Z1/Z2 over the kt-strip. LDS 16 KB, single-buffered async.
// zp layout: [par][which][NH][T] f32.
// ---------------------------------------------------------------------------
__global__ __launch_bounds__(256) void attn_a(
    const u16* __restrict__ qg, const u16* __restrict__ k1g,
    const u16* __restrict__ k2g, float* __restrict__ zp) {
    __shared__ __align__(16) u16 k1s[64 * 64];
    __shared__ __align__(16) u16 k2s[64 * 64];
    ATTN_MAP();

    const u16* qh = qg + (size_t)h * T_SEQ * HD;
    const u16* k1h = k1g + (size_t)h * T_SEQ * HD;
    const u16* k2h = k2g + (size_t)h * T_SEQ * HD;

    bf16x8 aq[2];
#pragma unroll
    for (int kk = 0; kk < 2; kk++)
        aq[kk] = *(const bf16x8*)(&qh[(size_t)(t0 + wm + lr) * HD + kk * 32 + quad * 8]);

    float z1a[4] = {0.f, 0.f, 0.f, 0.f}, z2a[4] = {0.f, 0.f, 0.f, 0.f};

    for (int kt = par; kt <= qt; kt += 2) {
        __syncthreads();   // protect LDS from previous iteration's readers
        stage_async<2>(k1h, (size_t)kt * 64, HD, 0, k1s, tid);
        stage_async<2>(k2h, (size_t)kt * 64, HD, 0, k2s, tid);
        __syncthreads();   // drains vmcnt -> data visible

        f32x4 sa[4], sb[4];
#pragma unroll
        for (int j = 0; j < 4; j++) { sa[j] = (f32x4){0.f,0.f,0.f,0.f}; sb[j] = (f32x4){0.f,0.f,0.f,0.f}; }
#pragma unroll
        for (int kk = 0; kk < 2; kk++) {
            const int co = ((kk * 4 + quad) ^ sw) * 8;
#pragma unroll
            for (int j = 0; j < 4; j++) {
                sa[j] = mfma16(aq[kk], frag(k1s, j * 16 + lr, co), sa[j]);
                sb[j] = mfma16(aq[kk], frag(k2s, j * 16 + lr, co), sb[j]);
            }
        }

        if (kt < qt) {
#pragma unroll
            for (int r = 0; r < 4; r++)
#pragma unroll
                for (int j = 0; j < 4; j++) {
                    z1a[r] += ex2(sa[j][r]);
                    z2a[r] += ex2(sb[j][r]);
                }
        } else {
#pragma unroll
            for (int r = 0; r < 4; r++) {
                const int grow = t0 + wm + quad * 4 + r;
#pragma unroll
                for (int j = 0; j < 4; j++) {
                    int gcol = kt * 64 + j * 16 + lr;
                    if (gcol <= grow) {
                        z1a[r] += ex2(sa[j][r]);
                        z2a[r] += ex2(sb[j][r]);
                    }
                }
            }
        }
    }

#pragma unroll
    for (int r = 0; r < 4; r++) {
        float s1 = qsum16(z1a[r]);
        float s2 = qsum16(z2a[r]);
        if (lr == 0) {
            int row = t0 + wm + quad * 4 + r;
            zp[((size_t)(par * 2 + 0) * NH + h) * T_SEQ + row] = s1;
            zp[((size_t)(par * 2 + 1) * NH + h) * T_SEQ + row] = s2;
        }
    }
}

// ---------------------------------------------------------------------------
// attn_b: P, partial |p| denom, partial O over the kt-strip.
// LDS 34 KB single-buffered -> 4 blocks/CU (16 waves/CU).
// opart: bf16 [par][T][DM]; dpart: f32 [par][NH][T].
// ---------------------------------------------------------------------------
__global__ __launch_bounds__(256) void attn_b(
    const u16* __restrict__ qg, const u16* __restrict__ k1g,
    const u16* __restrict__ k2g, const u16* __restrict__ vtg,
    const float* __restrict__ zp, const float* __restrict__ lamf,
    float* __restrict__ dpart, u16* __restrict__ opart) {
    __shared__ __align__(16) u16 k1s[64 * 64];
    __shared__ __align__(16) u16 k2s[64 * 64];
    __shared__ __align__(16) u16 vs[64 * 64];
    __shared__ __align__(16) u16 ps[4][16 * LS];
    ATTN_MAP();
    const float lam = lamf[h];

    const u16* qh = qg + (size_t)h * T_SEQ * HD;
    const u16* k1h = k1g + (size_t)h * T_SEQ * HD;
    const u16* k2h = k2g + (size_t)h * T_SEQ * HD;
    const u16* vh = vtg + (size_t)h * HD * T_SEQ;

    bf16x8 aq[2];
#pragma unroll
    for (int kk = 0; kk < 2; kk++)
        aq[kk] = *(const bf16x8*)(&qh[(size_t)(t0 + wm + lr) * HD + kk * 32 + quad * 8]);

    float z1i[4], z2i[4];
#pragma unroll
    for (int r = 0; r < 4; r++) {
        int row = t0 + wm + quad * 4 + r;
        float z1 = zp[((size_t)0 * NH + h) * T_SEQ + row] + zp[((size_t)2 * NH + h) * T_SEQ + row];
        float z2 = zp[((size_t)1 * NH + h) * T_SEQ + row] + zp[((size_t)3 * NH + h) * T_SEQ + row];
        z1i[r] = 1.f / z1;
        z2i[r] = lam / z2;
    }

    f32x4 oac[4];
#pragma unroll
    for (int j = 0; j < 4; j++) oac[j] = (f32x4){0.f, 0.f, 0.f, 0.f};
    float dacc[4] = {0.f, 0.f, 0.f, 0.f};

    for (int kt = par; kt <= qt; kt += 2) {
        __syncthreads();
        stage_async<2>(k1h, (size_t)kt * 64, HD, 0, k1s, tid);
        stage_async<2>(k2h, (size_t)kt * 64, HD, 0, k2s, tid);
        stage_async<2>(vh, 0, T_SEQ, (size_t)kt * 64, vs, tid);
        __syncthreads();

        f32x4 sa[4], sb[4];
#pragma unroll
        for (int j = 0; j < 4; j++) { sa[j] = (f32x4){0.f,0.f,0.f,0.f}; sb[j] = (f32x4){0.f,0.f,0.f,0.f}; }
#pragma unroll
        for (int kk = 0; kk < 2; kk++) {
            const int co = ((kk * 4 + quad) ^ sw) * 8;
#pragma unroll
            for (int j = 0; j < 4; j++) {
                sa[j] = mfma16(aq[kk], frag(k1s, j * 16 + lr, co), sa[j]);
                sb[j] = mfma16(aq[kk], frag(k2s, j * 16 + lr, co), sb[j]);
            }
        }

        if (kt < qt) {
#pragma unroll
            for (int r = 0; r < 4; r++)
#pragma unroll
                for (int j = 0; j < 4; j++) {
                    float p = ex2(sa[j][r]) * z1i[r] - ex2(sb[j][r]) * z2i[r];
                    dacc[r] += fabsf(p);
                    ps[wave][(quad * 4 + r) * LS + j * 16 + lr] = f2bf_t(p);
                }
        } else {
#pragma unroll
            for (int r = 0; r < 4; r++) {
                const int grow = t0 + wm + quad * 4 + r;
#pragma unroll
                for (int j = 0; j < 4; j++) {
                    int gcol = kt * 64 + j * 16 + lr;
                    float p = 0.f;
                    if (gcol <= grow)
                        p = ex2(sa[j][r]) * z1i[r] - ex2(sb[j][r]) * z2i[r];
                    dacc[r] += fabsf(p);
                    ps[wave][(quad * 4 + r) * LS + j * 16 + lr] = f2bf_t(p);
                }
            }
        }

        // PV: wave-local LDS round trip (DS pipe in-order per wave)
#pragma unroll
        for (int kk = 0; kk < 2; kk++) {
            bf16x8 pa = *(const bf16x8*)(&ps[wave][lr * LS + kk * 32 + quad * 8]);
            const int co = ((kk * 4 + quad) ^ sw) * 8;
#pragma unroll
            for (int j = 0; j < 4; j++)
                oac[j] = mfma16(pa, frag(vs, j * 16 + lr, co), oac[j]);
        }
    }

#pragma unroll
    for (int r = 0; r < 4; r++) {
        float ds = qsum16(dacc[r]);
        if (lr == 0) {
            int row = t0 + wm + quad * 4 + r;
            dpart[((size_t)par * NH + h) * T_SEQ + row] = ds;
        }
    }
#pragma unroll
    for (int j = 0; j < 4; j++)
#pragma unroll
        for (int r = 0; r < 4; r++) {
            int row = t0 + wm + quad * 4 + r;
            opart[(size_t)par * T_SEQ * DM + (size_t)row * DM + h * HD + j * 16 + lr] =
                f2bf(oac[j][r]);
        }
}

// ---------------------------------------------------------------------------
// normalize: ao[t][d] = (O0+O1) / max(d0+d1, 1e-6). 1024 blocks x 256 thr x 8.
// ---------------------------------------------------------------------------
__global__ __launch_bounds__(256) void normalize_o(
    const u16* __restrict__ opart, const float* __restrict__ dpart,
    u16* __restrict__ ao) {
    int g = blockIdx.x * 256 + threadIdx.x;
    int t = g >> 7;
    int cc = g & 127;
    int d0 = cc * 8;
    int h = d0 >> 6;
    float dsum = dpart[(size_t)h * T_SEQ + t] + dpart[(size_t)(NH + h) * T_SEQ + t];
    float rs = 1.f / fmaxf(dsum, 1e-6f);
    uint4 a = *(const uint4*)(&opart[(size_t)t * DM + d0]);
    uint4 bqq = *(const uint4*)(&opart[(size_t)T_SEQ * DM + (size_t)t * DM + d0]);
    const u32* au = (const u32*)&a;
    const u32* bu = (const u32*)&bqq;
    uint4 out;
    u32* ou = (u32*)&out;
#pragma unroll
    for (int i = 0; i < 4; i++) {
        float lo = (bf2f((u16)(au[i] & 0xFFFF)) + bf2f((u16)(bu[i] & 0xFFFF))) * rs;
        float hi = (bf2f((u16)(au[i] >> 16)) + bf2f((u16)(bu[i] >> 16))) * rs;
        ou[i] = pk2(lo, hi);
    }
    *(uint4*)(&ao[(size_t)t * DM + d0]) = out;
}

// ---------------------------------------------------------------------------
// Output GEMM: out = ao @ Wo^T. Tile 128x64, async dbuf, 256 blocks.
// ---------------------------------------------------------------------------
__global__ __launch_bounds__(256) void out_gemm(
    const u16* __restrict__ ab, const void* __restrict__ wo,
    const int* __restrict__ flag, void* __restrict__ outp) {
    __shared__ __align__(16) u16 As[2][128 * 64];
    __shared__ __align__(16) u16 Bs[2][64 * 64];

    const int f = *flag;
    const int n0 = blockIdx.x * 64;
    const int m0 = blockIdx.y * 128;
    const u16* wb = (const u16*)wo;
    const int tid = threadIdx.x;
    const int lane = tid & 63, wave = tid >> 6;
    const int lr = lane & 15, quad = lane >> 4;
    const int wm = (wave >> 1) * 64, wn = (wave & 1) * 32;
    const int sw = lr & 7;

    f32x4 acc[4][2];
#pragma unroll
    for (int i = 0; i < 4; i++)
#pragma unroll
        for (int j = 0; j < 2; j++) acc[i][j] = (f32x4){0.f, 0.f, 0.f, 0.f};

    if (f) {
        stage_async<4>(ab, m0, DM, 0, As[0], tid);
        stage_async<2>(wb, n0, DM, 0, Bs[0], tid);
    }
    for (int k0 = 0; k0 < DM; k0 += 64) {
        const int cur = (k0 >> 6) & 1;
        __syncthreads();
        if (f) {
            if (k0 + 64 < DM) {
                stage_async<4>(ab, m0, DM, k0 + 64, As[cur ^ 1], tid);
                stage_async<2>(wb, n0, DM, k0 + 64, Bs[cur ^ 1], tid);
            }
        } else {
            stage_sync<4>(ab, m0, DM, k0, As[cur], tid, 1);
            stage_sync<2>(wo, n0, DM, k0, Bs[cur], tid, 0);
            __syncthreads();
        }
#pragma unroll
        for (int kk = 0; kk < 2; kk++) {
            const int co = ((kk * 4 + quad) ^ sw) * 8;
            bf16x8 af[4], bfr[2];
#pragma unroll
            for (int i = 0; i < 4; i++) af[i] = frag(As[cur], wm + i * 16 + lr, co);
#pragma unroll
            for (int j = 0; j < 2; j++) bfr[j] = frag(Bs[cur], wn + j * 16 + lr, co);
#pragma unroll
            for (int i = 0; i < 4; i++)
#pragma unroll
                for (int j = 0; j < 2; j++) acc[i][j] = mfma16(af[i], bfr[j], acc[i][j]);
        }
    }

#pragma unroll
    for (int i = 0; i < 4; i++)
#pragma unroll
        for (int j = 0; j < 2; j++)
#pragma unroll
            for (int r = 0; r < 4; r++) {
                int t = m0 + wm + i * 16 + quad * 4 + r;
                int o = n0 + wn + j * 16 + lr;
                float val = acc[i][j][r];
                if (f)
                    ((u16*)outp)[(size_t)t * DM + o] = f2bf(val);
                else
                    ((float*)outp)[(size_t)t * DM + o] = val;
            }
}

extern "C" void kernel_launch(void* const* d_in, const int* in_sizes, int n_in,
                              void* d_out, int out_size, void* d_ws, size_t ws_size,
                              hipStream_t stream) {
    char* ws = (char*)d_ws;
    int* flag = (int*)(ws + 0);
    float* lamf = (float*)(ws + 256);
    float* zp    = (float*)(ws + ((size_t)1 << 20));   // [2][2][NH][T] = 512 KB
    float* dpart = (float*)(ws + ((size_t)2 << 20));   // [2][NH][T] = 256 KB
    u16* qd  = (u16*)(ws + ((size_t)16 << 20));  // [H][T][64]
    u16* k1d = (u16*)(ws + ((size_t)20 << 20));
    u16* k2d = (u16*)(ws + ((size_t)24 << 20));
    u16* vtd = (u16*)(ws + ((size_t)28 << 20));  // [H][64][T]
    u16* ao  = (u16*)(ws + ((size_t)32 << 20));  // [T][DM] bf16
    u16* opart = (u16*)(ws + ((size_t)36 << 20)); // [2][T][DM] bf16 = 8 MB

    detect_lam<<<1, 256, 0, stream>>>((const u16*)d_in[0], d_in[6], flag, lamf);
    qkv_gemm<<<dim3(64, 16), 256, 0, stream>>>(d_in[0], d_in[1], d_in[2], d_in[3],
                                               d_in[4], flag, qd, k1d, k2d, vtd);
    attn_a<<<dim3(1024), 256, 0, stream>>>(qd, k1d, k2d, zp);
    attn_b<<<dim3(1024), 256, 0, stream>>>(qd, k1d, k2d, vtd, zp, lamf, dpart, opart);
    normalize_o<<<dim3(1024), 256, 0, stream>>>(opart, dpart, ao);
    out_gemm<<<dim3(16, 16), 256, 0, stream>>>(ao, d_in[5], flag, d_out);
}